// Round 1
// baseline (148.343 us; speedup 1.0000x reference)
//
#include <hip/hip_runtime.h>

#define B 2
#define S 2048
#define A 16
#define H 1024
#define NH 16
#define HD 64
#define KT 32  // k-rows per block in scores kernel

// ---------------- kernel 1: masked mean over aspects -> h2_agg [B,H] -------
__global__ void k1_agg(const float* __restrict__ h2, const int* __restrict__ amask,
                       float* __restrict__ h2_agg) {
    int tid = blockIdx.x * blockDim.x + threadIdx.x;
    if (tid >= B * H) return;
    int b = tid / H, j = tid % H;
    float sum = 0.f; int cnt = 0;
#pragma unroll
    for (int a = 0; a < A; a++) {
        if (amask[b * A + a]) { sum += h2[((size_t)b * A + a) * H + j]; cnt++; }
    }
    float len = (float)(cnt > 0 ? cnt : 1);
    h2_agg[tid] = sum / len;
}

// ---------------- kernel 2: q[b,o] = h2_agg[b,:] . Wq[o,:]  (wave per o) ---
__global__ void k2_q(const float* __restrict__ h2_agg, const float* __restrict__ Wq,
                     float* __restrict__ q) {
    int gid = blockIdx.x * blockDim.x + threadIdx.x;
    int wid = gid >> 6, lane = gid & 63;
    if (wid >= B * H) return;
    int b = wid / H, o = wid % H;
    const float* hv = h2_agg + b * H;
    const float* wr = Wq + (size_t)o * H;
    float acc = 0.f;
#pragma unroll
    for (int t = 0; t < H / 64; t++) { int j = lane + 64 * t; acc += hv[j] * wr[j]; }
    for (int off = 32; off > 0; off >>= 1) acc += __shfl_down(acc, off);
    if (lane == 0) q[wid] = acc;
}

// ---------------- kernel 3: wq_eff[b,h,j] = scale * sum_d q[b,h*64+d]*Wk[h*64+d, j]
__global__ void k3_weff(const float* __restrict__ q, const float* __restrict__ Wk,
                        float* __restrict__ weff) {
    int gid = blockIdx.x * blockDim.x + threadIdx.x;
    if (gid >= B * NH * H) return;
    int b = gid / (NH * H); int r = gid % (NH * H); int h = r / H; int j = r % H;
    const float* qb = q + b * H + h * HD;
    float acc = 0.f;
#pragma unroll 8
    for (int d = 0; d < HD; d++) acc += qb[d] * Wk[(size_t)(h * HD + d) * H + j];
    weff[gid] = acc * 0.125f;  // scale = 64^-0.5
}

// ---------------- kernel 4: s[b,h,k] = wq_eff[b,h,:] . h1[b,k,:] ------------
__global__ __launch_bounds__(256) void k4_scores(const float* __restrict__ h1,
                                                 const float* __restrict__ weff,
                                                 float* __restrict__ s) {
    __shared__ float lds[NH * H];  // 64 KB: all 16 head weight vectors for batch b
    int b  = blockIdx.x / (S / KT);
    int kt = blockIdx.x % (S / KT);
    for (int i = threadIdx.x; i < NH * H; i += 256) lds[i] = weff[b * NH * H + i];
    __syncthreads();
    int wave = threadIdx.x >> 6, lane = threadIdx.x & 63;
    for (int kl = wave; kl < KT; kl += 4) {
        int k = kt * KT + kl;
        const float* row = h1 + ((size_t)b * S + k) * H;
        float x[16];
#pragma unroll
        for (int t = 0; t < 16; t++) x[t] = row[lane + 64 * t];
#pragma unroll
        for (int h = 0; h < NH; h++) {
            float acc = 0.f;
#pragma unroll
            for (int t = 0; t < 16; t++) acc += lds[h * H + lane + 64 * t] * x[t];
            for (int off = 32; off > 0; off >>= 1) acc += __shfl_down(acc, off);
            if (lane == 0) s[((size_t)b * NH + h) * S + k] = acc;
        }
    }
}

// ---------------- kernel 5: per-(b,h) masked softmax stats -----------------
__global__ void k5_stats(const float* __restrict__ s, const int* __restrict__ smask,
                         float* __restrict__ maxv, float* __restrict__ sumv) {
    int bh = blockIdx.x; int b = bh / NH;
    const float* srow = s + (size_t)bh * S;
    const int* mrow = smask + b * S;
    __shared__ float red[4];
    int lane = threadIdx.x & 63, wave = threadIdx.x >> 6;
    float mx = -3.4e38f;
    for (int k = threadIdx.x; k < S; k += 256) if (mrow[k]) mx = fmaxf(mx, srow[k]);
    for (int off = 32; off > 0; off >>= 1) mx = fmaxf(mx, __shfl_down(mx, off));
    if (lane == 0) red[wave] = mx;
    __syncthreads();
    float gmax = fmaxf(fmaxf(red[0], red[1]), fmaxf(red[2], red[3]));
    __syncthreads();
    float sum = 0.f;
    for (int k = threadIdx.x; k < S; k += 256) if (mrow[k]) sum += expf(srow[k] - gmax);
    for (int off = 32; off > 0; off >>= 1) sum += __shfl_down(sum, off);
    if (lane == 0) red[wave] = sum;
    __syncthreads();
    if (threadIdx.x == 0) { maxv[bh] = gmax; sumv[bh] = red[0] + red[1] + red[2] + red[3]; }
}

// ---------------- kernel 6: w[b,k] = mean_h softmax weight (masked -> 0) ---
__global__ void k6_w(const float* __restrict__ s, const int* __restrict__ smask,
                     const float* __restrict__ maxv, const float* __restrict__ sumv,
                     float* __restrict__ w) {
    int idx = blockIdx.x * blockDim.x + threadIdx.x;
    if (idx >= B * S) return;
    int b = idx / S, k = idx % S;
    float val = 0.f;
    if (smask[idx]) {
#pragma unroll
        for (int h = 0; h < NH; h++) {
            int bh = b * NH + h;
            val += expf(s[(size_t)bh * S + k] - maxv[bh]) / sumv[bh];
        }
        val *= (1.0f / NH);
    }
    w[idx] = val;
}

// ---------------- kernel 7: broadcast w[b,k] over all q rows ---------------
__global__ void k7_bcast(const float* __restrict__ w, float4* __restrict__ out) {
    int idx4 = blockIdx.x * blockDim.x + threadIdx.x;
    const int S4 = S / 4;
    if (idx4 >= B * S * S4) return;
    int k4 = idx4 % S4;
    int bq = idx4 / S4;          // bq = b*S + q
    int b  = bq / S;
    const float4* w4 = (const float4*)(w + b * S);
    out[idx4] = w4[k4];
}

extern "C" void kernel_launch(void* const* d_in, const int* in_sizes, int n_in,
                              void* d_out, int out_size, void* d_ws, size_t ws_size,
                              hipStream_t stream) {
    const float* h1    = (const float*)d_in[0];   // [B,S,H]
    const float* h2    = (const float*)d_in[1];   // [B,A,H]
    const int*   smask = (const int*)d_in[2];     // [B,S]
    const int*   amask = (const int*)d_in[3];     // [B,A]
    const float* Wq    = (const float*)d_in[4];   // [H,H]
    const float* Wk    = (const float*)d_in[5];   // [H,H]
    float* out = (float*)d_out;                   // [B,S,S]
    float* ws  = (float*)d_ws;

    float* h2_agg = ws;              // 2048
    float* q      = ws + 2048;       // 2048
    float* weff   = ws + 4096;       // 32768
    float* s      = ws + 36864;      // 65536
    float* maxv   = ws + 102400;     // 32
    float* sumv   = ws + 102432;     // 32
    float* w      = ws + 102464;     // 4096  (byte offset 409856, 16B aligned)

    k1_agg   <<<(B * H + 255) / 256, 256, 0, stream>>>(h2, amask, h2_agg);
    k2_q     <<<(B * H * 64) / 256, 256, 0, stream>>>(h2_agg, Wq, q);
    k3_weff  <<<(B * NH * H + 255) / 256, 256, 0, stream>>>(q, Wk, weff);
    k4_scores<<<B * (S / KT), 256, 0, stream>>>(h1, weff, s);
    k5_stats <<<B * NH, 256, 0, stream>>>(s, smask, maxv, sumv);
    k6_w     <<<(B * S + 255) / 256, 256, 0, stream>>>(s, smask, maxv, sumv, w);
    k7_bcast <<<(B * S * (S / 4) + 255) / 256, 256, 0, stream>>>(w, (float4*)out);
}